// Round 7
// baseline (375.161 us; speedup 1.0000x reference)
//
#include <hip/hip_runtime.h>
#include <hip/hip_bf16.h>
#include <cstdint>
#include <cstddef>

#define D 128
#define NGRAPH 64
#define DOUT 16

typedef __attribute__((ext_vector_type(8))) short short8;   // 8 bf16 = 4 VGPRs (MFMA A/B frag)
typedef __attribute__((ext_vector_type(4))) float float4v;  // MFMA C/D frag

__device__ inline float bf2f(unsigned short u) {
  union { unsigned int i; float f; } v; v.i = ((unsigned int)u) << 16; return v.f;
}
__device__ inline unsigned short f2bf(float f) {
  __hip_bfloat16 h = __float2bfloat16(f);
  union { __hip_bfloat16 h; unsigned short u; } v; v.h = h; return v.u;
}

// ---------------- CSR scans ----------------
__global__ void k_scanA(const int* __restrict__ deg, int* __restrict__ excl,
                        int* __restrict__ bsum, int n) {
  __shared__ int tmp[256];
  int tx = threadIdx.x;
  int i = blockIdx.x * 256 + tx;
  int v = (i < n) ? deg[i] : 0;
  tmp[tx] = v;
  __syncthreads();
  for (int off = 1; off < 256; off <<= 1) {
    int t = (tx >= off) ? tmp[tx - off] : 0;
    __syncthreads();
    tmp[tx] += t;
    __syncthreads();
  }
  if (i < n) excl[i] = tmp[tx] - v;
  if (tx == 255) bsum[blockIdx.x] = tmp[255];
}

__global__ void k_scanB(const int* __restrict__ bsum, int* __restrict__ boff, int nb) {
  __shared__ int tmp[256];
  int tx = threadIdx.x;
  int v = (tx < nb) ? bsum[tx] : 0;
  tmp[tx] = v;
  __syncthreads();
  for (int off = 1; off < 256; off <<= 1) {
    int t = (tx >= off) ? tmp[tx - off] : 0;
    __syncthreads();
    tmp[tx] += t;
    __syncthreads();
  }
  if (tx < nb) boff[tx] = tmp[tx] - v;
}

__global__ void k_scanC(const int* __restrict__ deg, const int* __restrict__ excl,
                        const int* __restrict__ boff, int* __restrict__ rowptr,
                        int* __restrict__ cur, float* __restrict__ inv, int n, int E) {
  int i = blockIdx.x * 256 + threadIdx.x;
  if (i < n) {
    int r = excl[i] + boff[i >> 8];
    rowptr[i] = r;
    cur[i] = r;
    int dg = deg[i];
    inv[i] = 1.0f / (float)(dg > 1 ? dg : 1);
  }
  if (i == 0) rowptr[n] = E;
}

__global__ void k_fill(const int* __restrict__ src, const int* __restrict__ dst,
                       int* __restrict__ cur, int* __restrict__ col, int E) {
  int e = blockIdx.x * 256 + threadIdx.x;
  if (e < E) {
    int pos = atomicAdd(&cur[dst[e]], 1);
    col[pos] = src[e];
  }
}

// ---------------- fused pre: dst histogram | x cast | weight hi/lo pack | bounds ----------
// grid: [0,histBlocks) hist; [+castBlocks) cast; [+384) wprep; last block bounds
__global__ void k_pre(const int* __restrict__ dst, int* __restrict__ deg, int E, int histBlocks,
                      const float* __restrict__ x, unsigned short* __restrict__ xb, int total4,
                      int castBlocks,
                      const float* __restrict__ w1l, const float* __restrict__ w1r,
                      const float* __restrict__ w2l, const float* __restrict__ w2r,
                      const float* __restrict__ w3l, const float* __restrict__ w3r,
                      unsigned short* __restrict__ wBp,
                      const int* __restrict__ batch, int* __restrict__ bnd, int n) {
  int b = blockIdx.x;
  if (b < histBlocks) {
    int e = b * 256 + threadIdx.x;
    if (e < E) atomicAdd(&deg[dst[e]], 1);
  } else if (b < histBlocks + castBlocks) {
    int i = (b - histBlocks) * 256 + threadIdx.x;
    if (i >= total4) return;
    float4 v = ((const float4*)x)[i];
    ushort4 o;
    o.x = f2bf(v.x); o.y = f2bf(v.y); o.z = f2bf(v.z); o.w = f2bf(v.w);
    ((ushort4*)xb)[i] = o;
  } else if (b < histBlocks + castBlocks + 384) {
    int t = (b - histBlocks - castBlocks) * 256 + threadIdx.x;  // < 3*128*256
    int layer = t >> 15;
    int rem = t & 32767;
    int colc = rem >> 8;
    int k = rem & 255;
    const float* wl = (layer == 0) ? w1l : (layer == 1) ? w2l : w3l;
    const float* wr = (layer == 0) ? w1r : (layer == 1) ? w2r : w3r;
    float v = (k < 128) ? wl[colc * 128 + k] : wr[colc * 128 + (k - 128)];
    unsigned short hi = f2bf(v);
    unsigned short lo = f2bf(v - bf2f(hi));
    int chunk = k >> 5, kk = k & 31;
    size_t base = (size_t)layer * 2 * 8 * 4096;
    wBp[base + ((size_t)0 * 8 + chunk) * 4096 + colc * 32 + kk] = hi;
    wBp[base + ((size_t)1 * 8 + chunk) * 4096 + colc * 32 + kk] = lo;
  } else {
    int g = threadIdx.x;
    if (g > NGRAPH) return;
    int lo = 0, hi = n;
    while (lo < hi) {
      int mid = (lo + hi) >> 1;
      if (batch[mid] < g) lo = mid + 1; else hi = mid;
    }
    bnd[g] = lo;
  }
}

// ---------------- fused layer: mean-aggregate (CSR gather) + dual-GEMM + bias + relu ------
// out[v,:] = relu( mean_{u->v} hin[u,:] @ Wl + hin[v,:] @ Wr + bl )
// Block: 128 nodes. Phase 1: gather-mean 128 rows into sM (LDS, bf16, full k-width).
// Phase 2: MFMA loop; chunks 0-3 A-frags from sM, 4-7 staged X from global; B hi/lo passes.
#define GROWS 128
#define SMST 136  // sM row stride (ushorts, 16B-multiple)
#define SAST 40   // sX/sB row stride
__global__ __launch_bounds__(256) void k_layer(
    const unsigned short* __restrict__ hin, const int* __restrict__ rowptr,
    const int* __restrict__ col, const float* __restrict__ inv,
    const unsigned short* __restrict__ wBp, const float* __restrict__ bl,
    unsigned short* __restrict__ out, int n) {
  __shared__ unsigned short sM[GROWS * SMST];       // 34816 B
  __shared__ unsigned short sX[GROWS * SAST];       // 10240 B
  __shared__ unsigned short sB[2][128 * SAST];      // 20480 B  -> 64 KB total
  const int tid = threadIdx.x;
  const int n0 = blockIdx.x * GROWS;

  // ---- phase 1: aggregation into sM ----
  {
    const int l16 = tid & 15;
    const int nsub = tid >> 4;  // 0..15
    for (int p = 0; p < 8; ++p) {
      int nl = p * 16 + nsub;
      int node = n0 + nl;
      float acc[8];
#pragma unroll
      for (int j = 0; j < 8; ++j) acc[j] = 0.f;
      if (node < n) {
        int beg = rowptr[node], end = rowptr[node + 1];
        int i = beg;
        for (; i + 4 <= end; i += 4) {
          int s0 = col[i + 0], s1 = col[i + 1], s2 = col[i + 2], s3 = col[i + 3];
          uint4 v0 = ((const uint4*)(hin + (size_t)s0 * D))[l16];
          uint4 v1 = ((const uint4*)(hin + (size_t)s1 * D))[l16];
          uint4 v2 = ((const uint4*)(hin + (size_t)s2 * D))[l16];
          uint4 v3 = ((const uint4*)(hin + (size_t)s3 * D))[l16];
          const unsigned short* u0 = (const unsigned short*)&v0;
          const unsigned short* u1 = (const unsigned short*)&v1;
          const unsigned short* u2 = (const unsigned short*)&v2;
          const unsigned short* u3 = (const unsigned short*)&v3;
#pragma unroll
          for (int j = 0; j < 8; ++j)
            acc[j] += (bf2f(u0[j]) + bf2f(u1[j])) + (bf2f(u2[j]) + bf2f(u3[j]));
        }
        for (; i < end; ++i) {
          int sn = col[i];
          uint4 v = ((const uint4*)(hin + (size_t)sn * D))[l16];
          const unsigned short* u = (const unsigned short*)&v;
#pragma unroll
          for (int j = 0; j < 8; ++j) acc[j] += bf2f(u[j]);
        }
        float iv = inv[node];
#pragma unroll
        for (int j = 0; j < 8; ++j) acc[j] *= iv;
      }
      uint4 o;
      unsigned short* ou = (unsigned short*)&o;
#pragma unroll
      for (int j = 0; j < 8; ++j) ou[j] = f2bf(acc[j]);
      *(uint4*)&sM[nl * SMST + l16 * 8] = o;
    }
  }

  // ---- phase 2: MFMA dual-GEMM ----
  const int w = tid >> 6;
  const int l = tid & 63;
  const int q = l >> 4;
  const int lr = l & 15;

  float4v acc[2][8];
#pragma unroll
  for (int rt = 0; rt < 2; ++rt)
#pragma unroll
    for (int ct = 0; ct < 8; ++ct) {
      float4v z = {0.f, 0.f, 0.f, 0.f};
      acc[rt][ct] = z;
    }

  for (int c = 0; c < 8; ++c) {
    __syncthreads();  // c=0: sM ready; c>0: prev reads of sX/sB done
    if (c >= 4) {
      // stage X chunk: 128 rows x 64 B
      int koff = (c & 3) * 32;
#pragma unroll
      for (int it = 0; it < 2; ++it) {
        int row = it * 64 + (tid >> 2);
        int piece = tid & 3;
        int node = n0 + row;
        uint4 v = make_uint4(0u, 0u, 0u, 0u);
        if (node < n) v = *(const uint4*)(hin + (size_t)node * D + koff + piece * 8);
        *(uint4*)&sX[row * SAST + piece * 8] = v;
      }
    }
    // stage B: 2 passes x 128 cols x 64 B
    {
      int p = tid >> 7;
      int colr = tid & 127;
      const unsigned short* srcw = wBp + ((size_t)p * 8 + c) * 4096 + colr * 32;
#pragma unroll
      for (int piece = 0; piece < 4; ++piece) {
        uint4 v = *(const uint4*)(srcw + piece * 8);
        *(uint4*)&sB[p][colr * SAST + piece * 8] = v;
      }
    }
    __syncthreads();
    short8 a0, a1;
    if (c < 4) {
      a0 = *(const short8*)&sM[(w * 32 + 0 + lr) * SMST + c * 32 + q * 8];
      a1 = *(const short8*)&sM[(w * 32 + 16 + lr) * SMST + c * 32 + q * 8];
    } else {
      a0 = *(const short8*)&sX[(w * 32 + 0 + lr) * SAST + q * 8];
      a1 = *(const short8*)&sX[(w * 32 + 16 + lr) * SAST + q * 8];
    }
#pragma unroll
    for (int ct = 0; ct < 8; ++ct) {
      short8 bh = *(const short8*)&sB[0][(ct * 16 + lr) * SAST + q * 8];
      short8 bo = *(const short8*)&sB[1][(ct * 16 + lr) * SAST + q * 8];
      acc[0][ct] = __builtin_amdgcn_mfma_f32_16x16x32_bf16(a0, bh, acc[0][ct], 0, 0, 0);
      acc[0][ct] = __builtin_amdgcn_mfma_f32_16x16x32_bf16(a0, bo, acc[0][ct], 0, 0, 0);
      acc[1][ct] = __builtin_amdgcn_mfma_f32_16x16x32_bf16(a1, bh, acc[1][ct], 0, 0, 0);
      acc[1][ct] = __builtin_amdgcn_mfma_f32_16x16x32_bf16(a1, bo, acc[1][ct], 0, 0, 0);
    }
  }
  // epilogue: bias + relu + bf16 store
#pragma unroll
  for (int ct = 0; ct < 8; ++ct) {
    float bv = bl[ct * 16 + lr];
#pragma unroll
    for (int rt = 0; rt < 2; ++rt) {
#pragma unroll
      for (int r = 0; r < 4; ++r) {
        int row = w * 32 + rt * 16 + q * 4 + r;
        int node = n0 + row;
        if (node < n) {
          float v = acc[rt][ct][r] + bv;
          v = fmaxf(v, 0.f);
          out[(size_t)node * D + ct * 16 + lr] = f2bf(v);
        }
      }
    }
  }
}

// ---------------- pooling: distributed run-length accumulate (bf16 reads) ----------------
__global__ void k_pool(const unsigned short* __restrict__ h, const int* __restrict__ batch,
                       float* __restrict__ gs, int n) {
  int c = threadIdx.x;  // 0..127 channel
  int n0 = blockIdx.x * 32;
  float acc = 0.f;
  int curg = -1;
  for (int j = 0; j < 32; ++j) {
    int node = n0 + j;
    if (node >= n) break;
    int g = batch[node];
    if (g != curg) {
      if (curg >= 0) atomicAdd(&gs[curg * D + c], acc);
      acc = 0.f;
      curg = g;
    }
    acc += bf2f(h[(size_t)node * D + c]);
  }
  if (curg >= 0) atomicAdd(&gs[curg * D + c], acc);
}

__global__ void k_final(const float* __restrict__ gs, const int* __restrict__ bnd,
                        const float* __restrict__ wlin, const float* __restrict__ blin,
                        float* __restrict__ out) {
  int t = blockIdx.x * 256 + threadIdx.x;
  if (t >= NGRAPH * DOUT) return;
  int g = t >> 4, o = t & 15;
  int cnt = bnd[g + 1] - bnd[g];
  float iv = 1.0f / (float)(cnt > 0 ? cnt : 1);
  float s = 0.f;
  for (int d = 0; d < D; ++d) s += gs[g * D + d] * wlin[o * D + d];
  out[t] = s * iv + blin[o];
}

// ---------------- launcher ----------------
extern "C" void kernel_launch(void* const* d_in, const int* in_sizes, int n_in,
                              void* d_out, int out_size, void* d_ws, size_t ws_size,
                              hipStream_t stream) {
  const float* x    = (const float*)d_in[0];
  const int*   ei   = (const int*)d_in[1];
  const int*   batch= (const int*)d_in[2];
  const float* w1l  = (const float*)d_in[3];
  const float* b1l  = (const float*)d_in[4];
  const float* w1r  = (const float*)d_in[5];
  const float* w2l  = (const float*)d_in[6];
  const float* b2l  = (const float*)d_in[7];
  const float* w2r  = (const float*)d_in[8];
  const float* w3l  = (const float*)d_in[9];
  const float* b3l  = (const float*)d_in[10];
  const float* w3r  = (const float*)d_in[11];
  const float* wlin = (const float*)d_in[12];
  const float* blin = (const float*)d_in[13];

  const int N = in_sizes[0] / D;   // 50000
  const int E = in_sizes[1] / 2;   // 600000
  const int* src = ei;
  const int* dst = ei + E;

  // ---- workspace layout (256B aligned) ----
  char* w = (char*)d_ws;
  auto align = [](size_t v) { return (v + 255) & ~(size_t)255; };
  size_t NBH = align((size_t)N * D * 2);  // bf16 node-feature buffer
  size_t off = 0;
  unsigned short* Xb = (unsigned short*)(w + off); off += NBH;
  unsigned short* Hb = (unsigned short*)(w + off); off += NBH;
  unsigned short* Hc = (unsigned short*)(w + off); off += NBH;
  int*   deg    = (int*)  (w + off); off += align((size_t)N * 4);
  int*   excl   = (int*)  (w + off); off += align((size_t)N * 4);
  int*   bsum   = (int*)  (w + off); off += 1024;
  int*   boff   = (int*)  (w + off); off += 1024;
  int*   rowptr = (int*)  (w + off); off += align((size_t)(N + 1) * 4);
  int*   cur    = (int*)  (w + off); off += align((size_t)N * 4);
  float* inv    = (float*)(w + off); off += align((size_t)N * 4);
  int*   col    = (int*)  (w + off); off += align((size_t)E * 4);
  unsigned short* wBp = (unsigned short*)(w + off); off += align((size_t)3 * 2 * 8 * 4096 * 2);
  float* gs     = (float*)(w + off); off += align((size_t)NGRAPH * D * 4);
  int*   bnd    = (int*)  (w + off); off += 512;
  (void)ws_size; (void)n_in; (void)out_size;

  const int nb = (N + 255) / 256;

  hipMemsetAsync(deg, 0, (size_t)N * 4, stream);
  hipMemsetAsync(gs, 0, (size_t)NGRAPH * D * 4, stream);

  // fused pre: hist | cast | wprep | bounds  (one launch)
  const int histBlocks = (E + 255) / 256;
  const int total4 = N * D / 4;
  const int castBlocks = (total4 + 255) / 256;
  k_pre<<<histBlocks + castBlocks + 384 + 1, 256, 0, stream>>>(
      dst, deg, E, histBlocks, x, Xb, total4, castBlocks,
      w1l, w1r, w2l, w2r, w3l, w3r, wBp, batch, bnd, N);

  // CSR scans + fill
  k_scanA<<<nb, 256, 0, stream>>>(deg, excl, bsum, N);
  k_scanB<<<1, 256, 0, stream>>>(bsum, boff, nb);
  k_scanC<<<nb, 256, 0, stream>>>(deg, excl, boff, rowptr, cur, inv, N, E);
  k_fill <<<(E + 255) / 256, 256, 0, stream>>>(src, dst, cur, col, E);

  const int gG = (N + GROWS - 1) / GROWS;  // 391 blocks
  const size_t WL = (size_t)2 * 8 * 4096;  // wBp elems per layer

  // fused layers: aggr+gemm
  k_layer<<<gG, 256, 0, stream>>>(Xb, rowptr, col, inv, wBp + 0 * WL, b1l, Hb, N);
  k_layer<<<gG, 256, 0, stream>>>(Hb, rowptr, col, inv, wBp + 1 * WL, b2l, Hc, N);
  k_layer<<<gG, 256, 0, stream>>>(Hc, rowptr, col, inv, wBp + 2 * WL, b3l, Hb, N);

  // global mean pool + final linear
  k_pool <<<(N + 31) / 32, 128, 0, stream>>>(Hb, batch, gs, N);
  k_final<<<4, 256, 0, stream>>>(gs, bnd, wlin, blin, (float*)d_out);
}

// Round 8
// 323.984 us; speedup vs baseline: 1.1580x; 1.1580x over previous
//
#include <hip/hip_runtime.h>
#include <hip/hip_bf16.h>
#include <cstdint>
#include <cstddef>

#define D 128
#define NGRAPH 64
#define DOUT 16

typedef __attribute__((ext_vector_type(8))) short short8;   // 8 bf16 = 4 VGPRs (MFMA A/B frag)
typedef __attribute__((ext_vector_type(4))) float float4v;  // MFMA C/D frag

__device__ inline float bf2f(unsigned short u) {
  union { unsigned int i; float f; } v; v.i = ((unsigned int)u) << 16; return v.f;
}
__device__ inline unsigned short f2bf(float f) {
  __hip_bfloat16 h = __float2bfloat16(f);
  union { __hip_bfloat16 h; unsigned short u; } v; v.h = h; return v.u;
}

// ---------------- fused pre: dst histogram | x cast | weight hi/lo pack | bounds ----------
// grid: [0,histBlocks) hist; [+castBlocks) cast; [+384) wprep; last block bounds (+gcount=0)
__global__ void k_pre(const int* __restrict__ dst, int* __restrict__ deg, int E, int histBlocks,
                      const float* __restrict__ x, unsigned short* __restrict__ xb, int total4,
                      int castBlocks,
                      const float* __restrict__ w1l, const float* __restrict__ w1r,
                      const float* __restrict__ w2l, const float* __restrict__ w2r,
                      const float* __restrict__ w3l, const float* __restrict__ w3r,
                      unsigned short* __restrict__ wBp,
                      const int* __restrict__ batch, int* __restrict__ bnd,
                      int* __restrict__ gcount, int n) {
  int b = blockIdx.x;
  if (b < histBlocks) {
    int e = b * 256 + threadIdx.x;
    if (e < E) atomicAdd(&deg[dst[e]], 1);
  } else if (b < histBlocks + castBlocks) {
    int i = (b - histBlocks) * 256 + threadIdx.x;
    if (i >= total4) return;
    float4 v = ((const float4*)x)[i];
    ushort4 o;
    o.x = f2bf(v.x); o.y = f2bf(v.y); o.z = f2bf(v.z); o.w = f2bf(v.w);
    ((ushort4*)xb)[i] = o;
  } else if (b < histBlocks + castBlocks + 384) {
    int t = (b - histBlocks - castBlocks) * 256 + threadIdx.x;  // < 3*128*256
    int layer = t >> 15;
    int rem = t & 32767;
    int colc = rem >> 8;
    int k = rem & 255;
    const float* wl = (layer == 0) ? w1l : (layer == 1) ? w2l : w3l;
    const float* wr = (layer == 0) ? w1r : (layer == 1) ? w2r : w3r;
    float v = (k < 128) ? wl[colc * 128 + k] : wr[colc * 128 + (k - 128)];
    unsigned short hi = f2bf(v);
    unsigned short lo = f2bf(v - bf2f(hi));
    int chunk = k >> 5, kk = k & 31;
    size_t base = (size_t)layer * 2 * 8 * 4096;
    wBp[base + ((size_t)0 * 8 + chunk) * 4096 + colc * 32 + kk] = hi;
    wBp[base + ((size_t)1 * 8 + chunk) * 4096 + colc * 32 + kk] = lo;
  } else {
    int g = threadIdx.x;
    if (g == NGRAPH + 1) { *gcount = 0; return; }  // zero allocator for k_offsets
    if (g > NGRAPH) return;
    int lo = 0, hi = n;
    while (lo < hi) {
      int mid = (lo + hi) >> 1;
      if (batch[mid] < g) lo = mid + 1; else hi = mid;
    }
    bnd[g] = lo;
  }
}

// ---------------- CSR region allocation (order-free: no prefix-sum chain) ----------------
// Each node gets a disjoint [start, start+deg) region via one atomicAdd per WAVE
// (wave-level shfl_up prefix of degrees). Region order across nodes is arbitrary -> fine.
__global__ __launch_bounds__(256) void k_offsets(
    const int* __restrict__ deg, int* __restrict__ startp, int* __restrict__ endp,
    int* __restrict__ cur, float* __restrict__ inv, int* __restrict__ gcount, int n) {
  int i = blockIdx.x * 256 + threadIdx.x;
  int d = (i < n) ? deg[i] : 0;
  int lane = threadIdx.x & 63;
  int pre = d;  // inclusive prefix within wave
#pragma unroll
  for (int off = 1; off < 64; off <<= 1) {
    int t = __shfl_up(pre, off, 64);
    if (lane >= off) pre += t;
  }
  int total = __shfl(pre, 63, 64);
  int base = 0;
  if (lane == 63) base = atomicAdd(gcount, total);
  base = __shfl(base, 63, 64);
  int start = base + pre - d;
  if (i < n) {
    startp[i] = start;
    endp[i] = start + d;
    cur[i] = start;
    inv[i] = 1.0f / (float)(d > 1 ? d : 1);
  }
}

__global__ void k_fill(const int* __restrict__ src, const int* __restrict__ dst,
                       int* __restrict__ cur, int* __restrict__ col, int E) {
  int e = blockIdx.x * 256 + threadIdx.x;
  if (e < E) {
    int pos = atomicAdd(&cur[dst[e]], 1);
    col[pos] = src[e];
  }
}

// ---------------- mean aggregation via CSR (bf16 gather, 4-way MLP unroll) ----------------
__global__ __launch_bounds__(256) void k_aggr(
    const unsigned short* __restrict__ hin, const int* __restrict__ startp,
    const int* __restrict__ endp, const int* __restrict__ col,
    const float* __restrict__ inv, unsigned short* __restrict__ M, int n) {
  int tid = threadIdx.x;
  int node = blockIdx.x * 16 + (tid >> 4);
  int l16 = tid & 15;  // 16 B = 8 bf16 per lane
  if (node >= n) return;
  int beg = startp[node], end = endp[node];
  float acc[8];
#pragma unroll
  for (int j = 0; j < 8; ++j) acc[j] = 0.f;
  int i = beg;
  for (; i + 4 <= end; i += 4) {
    int s0 = col[i + 0], s1 = col[i + 1], s2 = col[i + 2], s3 = col[i + 3];
    uint4 v0 = ((const uint4*)(hin + (size_t)s0 * D))[l16];
    uint4 v1 = ((const uint4*)(hin + (size_t)s1 * D))[l16];
    uint4 v2 = ((const uint4*)(hin + (size_t)s2 * D))[l16];
    uint4 v3 = ((const uint4*)(hin + (size_t)s3 * D))[l16];
    const unsigned short* u0 = (const unsigned short*)&v0;
    const unsigned short* u1 = (const unsigned short*)&v1;
    const unsigned short* u2 = (const unsigned short*)&v2;
    const unsigned short* u3 = (const unsigned short*)&v3;
#pragma unroll
    for (int j = 0; j < 8; ++j)
      acc[j] += (bf2f(u0[j]) + bf2f(u1[j])) + (bf2f(u2[j]) + bf2f(u3[j]));
  }
  for (; i < end; ++i) {
    int sn = col[i];
    uint4 v = ((const uint4*)(hin + (size_t)sn * D))[l16];
    const unsigned short* u = (const unsigned short*)&v;
#pragma unroll
    for (int j = 0; j < 8; ++j) acc[j] += bf2f(u[j]);
  }
  float iv = inv[node];
  uint4 o;
  unsigned short* ou = (unsigned short*)&o;
#pragma unroll
  for (int j = 0; j < 8; ++j) ou[j] = f2bf(acc[j] * iv);
  ((uint4*)(M + (size_t)node * D))[l16] = o;
}

// ---------------- MFMA dual-GEMM + bias + relu ----------------
// out[node,:] = relu([M|X][node,:] @ B + bl), B = Bhi + Blo (weight hi/lo split).
// Tile: 128 nodes x 128 cols; 4 waves, each 32 rows (2 x 16-row frags) x 8 col-tiles.
// K = 256 in 8 chunks of 32; per chunk, 2 MFMA passes (hi, lo) into same fp32 acc.
#define GROWS 128
#define SAST 40  // LDS row stride in ushorts (80 B)
__global__ __launch_bounds__(256) void k_gemm(
    const unsigned short* __restrict__ M, const unsigned short* __restrict__ X,
    const unsigned short* __restrict__ wBp, const float* __restrict__ bl,
    unsigned short* __restrict__ out, int n) {
  __shared__ unsigned short sA[GROWS * SAST];
  __shared__ unsigned short sB[2][128 * SAST];
  const int tid = threadIdx.x;
  const int n0 = blockIdx.x * GROWS;
  const int w = tid >> 6;
  const int l = tid & 63;
  const int q = l >> 4;
  const int lr = l & 15;

  float4v acc[2][8];
#pragma unroll
  for (int rt = 0; rt < 2; ++rt)
#pragma unroll
    for (int ct = 0; ct < 8; ++ct) {
      float4v z = {0.f, 0.f, 0.f, 0.f};
      acc[rt][ct] = z;
    }

  for (int c = 0; c < 8; ++c) {
    __syncthreads();
    // stage A: 128 rows x 64 B (chunks 0-3 from M, 4-7 from X)
    {
      const unsigned short* srcbase = (c < 4) ? M : X;
      int koff = (c & 3) * 32;
#pragma unroll
      for (int it = 0; it < 2; ++it) {
        int row = it * 64 + (tid >> 2);
        int piece = tid & 3;
        int node = n0 + row;
        uint4 v = make_uint4(0u, 0u, 0u, 0u);
        if (node < n) v = *(const uint4*)(srcbase + (size_t)node * D + koff + piece * 8);
        *(uint4*)&sA[row * SAST + piece * 8] = v;
      }
    }
    // stage B: 2 passes x 128 cols x 64 B
    {
      int p = tid >> 7;
      int colr = tid & 127;
      const unsigned short* srcw = wBp + ((size_t)p * 8 + c) * 4096 + colr * 32;
#pragma unroll
      for (int piece = 0; piece < 4; ++piece) {
        uint4 v = *(const uint4*)(srcw + piece * 8);
        *(uint4*)&sB[p][colr * SAST + piece * 8] = v;
      }
    }
    __syncthreads();
    short8 a0 = *(const short8*)&sA[(w * 32 + 0 + lr) * SAST + q * 8];
    short8 a1 = *(const short8*)&sA[(w * 32 + 16 + lr) * SAST + q * 8];
#pragma unroll
    for (int ct = 0; ct < 8; ++ct) {
      short8 bh = *(const short8*)&sB[0][(ct * 16 + lr) * SAST + q * 8];
      short8 bo = *(const short8*)&sB[1][(ct * 16 + lr) * SAST + q * 8];
      acc[0][ct] = __builtin_amdgcn_mfma_f32_16x16x32_bf16(a0, bh, acc[0][ct], 0, 0, 0);
      acc[0][ct] = __builtin_amdgcn_mfma_f32_16x16x32_bf16(a0, bo, acc[0][ct], 0, 0, 0);
      acc[1][ct] = __builtin_amdgcn_mfma_f32_16x16x32_bf16(a1, bh, acc[1][ct], 0, 0, 0);
      acc[1][ct] = __builtin_amdgcn_mfma_f32_16x16x32_bf16(a1, bo, acc[1][ct], 0, 0, 0);
    }
  }
  // epilogue: bias + relu + bf16 store
#pragma unroll
  for (int ct = 0; ct < 8; ++ct) {
    float bv = bl[ct * 16 + lr];
#pragma unroll
    for (int rt = 0; rt < 2; ++rt) {
#pragma unroll
      for (int r = 0; r < 4; ++r) {
        int row = w * 32 + rt * 16 + q * 4 + r;
        int node = n0 + row;
        if (node < n) {
          float v = acc[rt][ct][r] + bv;
          v = fmaxf(v, 0.f);
          out[(size_t)node * D + ct * 16 + lr] = f2bf(v);
        }
      }
    }
  }
}

// ---------------- pooling: distributed run-length accumulate (bf16 reads) ----------------
__global__ void k_pool(const unsigned short* __restrict__ h, const int* __restrict__ batch,
                       float* __restrict__ gs, int n) {
  int c = threadIdx.x;  // 0..127 channel
  int n0 = blockIdx.x * 32;
  float acc = 0.f;
  int curg = -1;
  for (int j = 0; j < 32; ++j) {
    int node = n0 + j;
    if (node >= n) break;
    int g = batch[node];
    if (g != curg) {
      if (curg >= 0) atomicAdd(&gs[curg * D + c], acc);
      acc = 0.f;
      curg = g;
    }
    acc += bf2f(h[(size_t)node * D + c]);
  }
  if (curg >= 0) atomicAdd(&gs[curg * D + c], acc);
}

__global__ void k_final(const float* __restrict__ gs, const int* __restrict__ bnd,
                        const float* __restrict__ wlin, const float* __restrict__ blin,
                        float* __restrict__ out) {
  int t = blockIdx.x * 256 + threadIdx.x;
  if (t >= NGRAPH * DOUT) return;
  int g = t >> 4, o = t & 15;
  int cnt = bnd[g + 1] - bnd[g];
  float iv = 1.0f / (float)(cnt > 0 ? cnt : 1);
  float s = 0.f;
  for (int d = 0; d < D; ++d) s += gs[g * D + d] * wlin[o * D + d];
  out[t] = s * iv + blin[o];
}

// ---------------- launcher ----------------
extern "C" void kernel_launch(void* const* d_in, const int* in_sizes, int n_in,
                              void* d_out, int out_size, void* d_ws, size_t ws_size,
                              hipStream_t stream) {
  const float* x    = (const float*)d_in[0];
  const int*   ei   = (const int*)d_in[1];
  const int*   batch= (const int*)d_in[2];
  const float* w1l  = (const float*)d_in[3];
  const float* b1l  = (const float*)d_in[4];
  const float* w1r  = (const float*)d_in[5];
  const float* w2l  = (const float*)d_in[6];
  const float* b2l  = (const float*)d_in[7];
  const float* w2r  = (const float*)d_in[8];
  const float* w3l  = (const float*)d_in[9];
  const float* b3l  = (const float*)d_in[10];
  const float* w3r  = (const float*)d_in[11];
  const float* wlin = (const float*)d_in[12];
  const float* blin = (const float*)d_in[13];

  const int N = in_sizes[0] / D;   // 50000
  const int E = in_sizes[1] / 2;   // 600000
  const int* src = ei;
  const int* dst = ei + E;

  // ---- workspace layout (256B aligned) ----
  char* w = (char*)d_ws;
  auto align = [](size_t v) { return (v + 255) & ~(size_t)255; };
  size_t NBH = align((size_t)N * D * 2);  // bf16 node-feature buffer
  size_t off = 0;
  unsigned short* Xb = (unsigned short*)(w + off); off += NBH;
  unsigned short* Ma = (unsigned short*)(w + off); off += NBH;
  unsigned short* Hb = (unsigned short*)(w + off); off += NBH;
  unsigned short* Hc = (unsigned short*)(w + off); off += NBH;
  int*   deg    = (int*)  (w + off); off += align((size_t)N * 4);
  int*   startp = (int*)  (w + off); off += align((size_t)N * 4);
  int*   endp   = (int*)  (w + off); off += align((size_t)N * 4);
  int*   cur    = (int*)  (w + off); off += align((size_t)N * 4);
  float* inv    = (float*)(w + off); off += align((size_t)N * 4);
  int*   col    = (int*)  (w + off); off += align((size_t)E * 4);
  unsigned short* wBp = (unsigned short*)(w + off); off += align((size_t)3 * 2 * 8 * 4096 * 2);
  float* gs     = (float*)(w + off); off += align((size_t)NGRAPH * D * 4);
  int*   bnd    = (int*)  (w + off); off += 512;
  int*   gcount = (int*)  (w + off); off += 256;
  (void)ws_size; (void)n_in; (void)out_size;

  hipMemsetAsync(deg, 0, (size_t)N * 4, stream);
  hipMemsetAsync(gs, 0, (size_t)NGRAPH * D * 4, stream);

  // fused pre: hist | cast | wprep | bounds (+gcount=0)  (one launch)
  const int histBlocks = (E + 255) / 256;
  const int total4 = N * D / 4;
  const int castBlocks = (total4 + 255) / 256;
  k_pre<<<histBlocks + castBlocks + 384 + 1, 256, 0, stream>>>(
      dst, deg, E, histBlocks, x, Xb, total4, castBlocks,
      w1l, w1r, w2l, w2r, w3l, w3r, wBp, batch, bnd, gcount, N);

  // CSR: order-free region allocation + fill
  k_offsets<<<(N + 255) / 256, 256, 0, stream>>>(deg, startp, endp, cur, inv, gcount, N);
  k_fill   <<<(E + 255) / 256, 256, 0, stream>>>(src, dst, cur, col, E);

  const int gA = (N + 15) / 16;            // aggr grid
  const int gG = (N + GROWS - 1) / GROWS;  // gemm grid (391)
  const size_t WL = (size_t)2 * 8 * 4096;  // wBp elems per layer

  // layer 1
  k_aggr<<<gA, 256, 0, stream>>>(Xb, startp, endp, col, inv, Ma, N);
  k_gemm<<<gG, 256, 0, stream>>>(Ma, Xb, wBp + 0 * WL, b1l, Hb, N);
  // layer 2
  k_aggr<<<gA, 256, 0, stream>>>(Hb, startp, endp, col, inv, Ma, N);
  k_gemm<<<gG, 256, 0, stream>>>(Ma, Hb, wBp + 1 * WL, b2l, Hc, N);
  // layer 3
  k_aggr<<<gA, 256, 0, stream>>>(Hc, startp, endp, col, inv, Ma, N);
  k_gemm<<<gG, 256, 0, stream>>>(Ma, Hc, wBp + 2 * WL, b3l, Hb, N);

  // global mean pool + final linear
  k_pool <<<(N + 31) / 32, 128, 0, stream>>>(Hb, batch, gs, N);
  k_final<<<4, 256, 0, stream>>>(gs, bnd, wlin, blin, (float*)d_out);
}